// Round 1
// baseline (2775.284 us; speedup 1.0000x reference)
//
#include <hip/hip_runtime.h>
#include <cstdint>

// CVFRLayer: x_{t+1} = (1-dt)x + dt*(nl(x) @ B) + sqrt(dt)*eps*(noise_t @ G^T)
// B = (A @ (I-P) + P)^T  with P block-diagonal (16 blocks of 128, value pval).
// Key identity: B[k,n] = A[n,k] - pval*rowblocksum(A,n,blk(k)) + pval*[blk(n)==blk(k)]
// => GEMM with B-transposed operand stored [N][K] is built from A's ROWS (cheap prep).
// Noise term: (n @ G^T)[m,j] = sum_k n[m,k]*G[j,k] => B-operand is G's rows verbatim.
// Fused per-step GEMM: C[m,n] = sum_{k<2048} Y[m,k]*BTs[n,k] + sum_{k<2048} Nb[m,k]*Gs[n,k]
// with dt folded into BTs and sqrt(dt)*eps folded into Gs.
//
// v2 (this round): 8 waves/block (2 waves/SIMD for latency hiding), K-split-8 with
// wave-private K=32 chunks (4KB+4KB, double buffered = 128 KiB), XCD-aware block
// swizzle (each XCD owns a 256-col n-slice; footprint 10->6 MB). 8-way LDS reduction.

typedef unsigned short ushort_t;
typedef __bf16 bf16x8 __attribute__((ext_vector_type(8)));
typedef float f32x4 __attribute__((ext_vector_type(4)));
typedef unsigned short u16x4 __attribute__((ext_vector_type(4)));
typedef unsigned short u16x8 __attribute__((ext_vector_type(8)));

#define SZ 2048
#define BATCH 512
#define NSTEPS 100

static constexpr float DT = 0.03f;
static constexpr float GAM = 0.125f;
// pval = 1/((sqrt(128)+1e-8)^2) = 1/(128 + 2*sqrt(128)*1e-8 + 1e-16)
static constexpr float PVAL = (float)(1.0 / (128.0 + 2.2627416997969522e-07));
// sqrt(dt)*epsilon
static constexpr float CNOISE = 0.017320508075688773f;

__device__ __forceinline__ unsigned short f2bf(float f) {
    unsigned int u = __builtin_bit_cast(unsigned int, f);
    return (unsigned short)((u + 0x7fffu + ((u >> 16) & 1u)) >> 16);
}

__device__ __forceinline__ void async16(const void* g, void* l) {
    // global->LDS DMA, 16B per lane; LDS dest = wave-uniform base + lane*16
    __builtin_amdgcn_global_load_lds(
        (__attribute__((address_space(1))) void*)(uintptr_t)g,
        (__attribute__((address_space(3))) void*)(uint32_t)(uintptr_t)l,
        16, 0, 0);
}

// ---------------- prep: build BTs (dt-scaled) and Gs (cnoise-scaled) in bf16 -------------
__global__ __launch_bounds__(256) void prep_kernel(const float* __restrict__ A,
                                                   const float* __restrict__ G,
                                                   ushort_t* __restrict__ BTs,
                                                   ushort_t* __restrict__ Gs) {
    const int n = blockIdx.x;
    const int t = threadIdx.x;
    __shared__ float s16[16];
    const float* arow = A + (size_t)n * SZ;
    f32x4 a0 = *(const f32x4*)(arow + t * 8);
    f32x4 a1 = *(const f32x4*)(arow + t * 8 + 4);
    float ps = a0[0] + a0[1] + a0[2] + a0[3] + a1[0] + a1[1] + a1[2] + a1[3];
#pragma unroll
    for (int m = 1; m < 16; m <<= 1) ps += __shfl_xor(ps, m, 64);
    if ((t & 15) == 0) s16[t >> 4] = ps * PVAL;   // thread t covers elems t*8..t*8+7, all in seg t/16
    __syncthreads();
    const int seg = t >> 4;
    const float s = s16[seg];
    const float diag = (seg == (n >> 7)) ? PVAL : 0.0f;
    float av[8] = {a0[0], a0[1], a0[2], a0[3], a1[0], a1[1], a1[2], a1[3]};
    u16x8 ov;
#pragma unroll
    for (int i = 0; i < 8; ++i) ov[i] = f2bf(DT * (av[i] - s + diag));
    *(u16x8*)&BTs[(size_t)n * SZ + t * 8] = ov;

    const float* grow = G + (size_t)n * SZ;
    f32x4 g0 = *(const f32x4*)(grow + t * 8);
    f32x4 g1 = *(const f32x4*)(grow + t * 8 + 4);
    float gv[8] = {g0[0], g0[1], g0[2], g0[3], g1[0], g1[1], g1[2], g1[3]};
    u16x8 og;
#pragma unroll
    for (int i = 0; i < 8; ++i) og[i] = f2bf(CNOISE * gv[i]);
    *(u16x8*)&Gs[(size_t)n * SZ + t * 8] = og;
}

// ---------------- init: xbuf = x, Y0 = bf16(nl(x)), N0 = bf16(noise[0]) -----------------
__global__ __launch_bounds__(256) void init_kernel(const float* __restrict__ x,
                                                   const float* __restrict__ noise,
                                                   float* __restrict__ xbuf,
                                                   ushort_t* __restrict__ Y0,
                                                   ushort_t* __restrict__ N0) {
    const size_t i = ((size_t)blockIdx.x * 256 + threadIdx.x) * 4;
    const size_t NX = (size_t)BATCH * SZ;
    if (i < NX) {
        f32x4 xv = *(const f32x4*)(x + i);
        *(f32x4*)(xbuf + i) = xv;
        u16x4 yv;
#pragma unroll
        for (int e = 0; e < 4; ++e) {
            float x2 = xv[e] * xv[e];
            yv[e] = f2bf(x2 / (GAM + x2));
        }
        *(u16x4*)(Y0 + i) = yv;
    } else {
        size_t j = i - NX;
        f32x4 nv = *(const f32x4*)(noise + j);
        u16x4 nb;
#pragma unroll
        for (int e = 0; e < 4; ++e) nb[e] = f2bf(nv[e]);
        *(u16x4*)(N0 + j) = nb;
    }
}

// ---------------- step: fused dual-GEMM (K=4096) + epilogue ------------------------------
// Grid 256 blocks (XCD-swizzled), 512 threads (8 waves). 64x64 output tile per block.
// Each wave owns a K=512 octile (waves 0-3: Y@BTs quarters; 4-7: Nb@Gs quarters) with
// wave-PRIVATE double-buffered LDS chunks (K=32: A 4KB + B 4KB) -> no __syncthreads in
// the K-loop; 2 waves/SIMD provide TLP latency hiding. XOR swizzle (p^(r&3)^((r>>2)&3))
// applied on the global-fetch side so ds_read_b128 frag reads are exactly 2-way (free).
__global__ __launch_bounds__(512) void step_kernel(
    const ushort_t* __restrict__ Ycur, const ushort_t* __restrict__ Ncur,
    const ushort_t* __restrict__ BTs, const ushort_t* __restrict__ Gs,
    const float* xin, float* xout,
    ushort_t* __restrict__ Ynext, const float* __restrict__ noise_next,
    ushort_t* __restrict__ Nnext, int do_noise) {
    extern __shared__ ushort_t smem[];  // 139264 B: K-loop 8w*16KB=128KB; epilogue 136KB
    const int tid = threadIdx.x;
    const int w = tid >> 6;
    const int l = tid & 63;

    // XCD swizzle: consecutive dispatch ids round-robin XCDs (id&7). Give each XCD a
    // contiguous 256-col n-slice across all 512 rows: B-slice 2MB + A 4MB = 6MB footprint.
    const int id = blockIdx.x;
    const int r5 = id >> 3;                       // 0..31
    const int n0 = (((id & 7) << 2) + (r5 & 3)) << 6;
    const int m0 = (r5 >> 2) << 6;

    // wave w -> K-octile of combined K=4096 (bytes within row: w*1024)
    const char* Ag;
    const char* Bg;
    {
        const ushort_t* As;
        const ushort_t* Bs;
        int kb0;
        if (w < 4) { As = Ycur; Bs = BTs; kb0 = w * 1024; }        // 512 bf16 elems
        else       { As = Ncur; Bs = Gs;  kb0 = (w - 4) * 1024; }
        Ag = (const char*)As + (size_t)m0 * 4096 + kb0;  // row stride 2048 bf16 = 4096B
        Bg = (const char*)Bs + (size_t)n0 * 4096 + kb0;
    }
    ushort_t* waveLds = smem + w * 8192;  // 16KB per wave (in ushorts)

    // staging: lane l -> LDS row (l>>2), 16B slot (l&3). Global chunk fetched at this
    // slot is pre-swizzled: p_glob = (l&3) ^ (row&3) ^ ((row>>4 within-instr rows...)=l>>4)
    const int pg = (l & 3) ^ ((l >> 2) & 3) ^ (l >> 4);
    const int sgo = (l >> 2) * 4096 + pg * 16;

    f32x4 acc[4][4] = {};

    auto stage = [&](int ci, int b) {
        const char* Ac = Ag + ci * 64;            // K=32 -> 64 bytes
        const char* Bc = Bg + ci * 64;
        ushort_t* dA = waveLds + b * 4096;        // buf: A 4KB | B 4KB
        ushort_t* dB = dA + 2048;
#pragma unroll
        for (int i = 0; i < 4; ++i) {             // 16 rows per DMA
            async16(Ac + i * 65536 + sgo, dA + i * 512);
            async16(Bc + i * 65536 + sgo, dB + i * 512);
        }
    };

    const int lr = l & 15;
    const int q8 = l >> 4;
    // read-side swizzle: row = f*16+lr => row&3 = lr&3, (row>>2)&3 = (lr>>2)&3 (f-indep)
    const int slotoff = ((q8 ^ (lr & 3) ^ ((lr >> 2) & 3)) << 4);

    auto compute = [&](int b) {
        const char* TA = (const char*)waveLds + b * 8192;
        const char* TB = TA + 4096;
        bf16x8 af[4], bfv[4];
#pragma unroll
        for (int f = 0; f < 4; ++f) {
            const int rowb = f * 1024 + lr * 64;  // row stride 64B (32 bf16)
            af[f] = *(const bf16x8*)(TA + rowb + slotoff);
            bfv[f] = *(const bf16x8*)(TB + rowb + slotoff);
        }
#pragma unroll
        for (int fr = 0; fr < 4; ++fr)
#pragma unroll
            for (int fc = 0; fc < 4; ++fc)
                acc[fr][fc] = __builtin_amdgcn_mfma_f32_16x16x32_bf16(
                    af[fr], bfv[fc], acc[fr][fc], 0, 0, 0);
    };

    stage(0, 0);
#pragma unroll 2
    for (int ci = 0; ci < 16; ++ci) {
        if (ci < 15) {
            stage(ci + 1, (ci + 1) & 1);
            // oldest-8 (= chunk ci's DMAs) drained; chunk ci+1's 8 stay in flight
            asm volatile("s_waitcnt vmcnt(8)" ::: "memory");
        } else {
            asm volatile("s_waitcnt vmcnt(0)" ::: "memory");
        }
        compute(ci & 1);
    }

    // cross-wave 8-way K-split reduction through LDS (padded stride 68 floats)
    __syncthreads();
    float* redF = (float*)smem;
    {
        const int base = w * 4352;
#pragma unroll
        for (int fr = 0; fr < 4; ++fr)
#pragma unroll
            for (int fc = 0; fc < 4; ++fc) {
                const int c = fc * 16 + lr;
                const int rb = fr * 16 + q8 * 4;  // C/D: row=(lane>>4)*4+reg, col=lane&15
#pragma unroll
                for (int reg = 0; reg < 4; ++reg)
                    redF[base + (rb + reg) * 68 + c] = acc[fr][fc][reg];
            }
    }
    __syncthreads();
    {
        const int r = tid >> 3;            // 0..63
        const int c0 = (tid & 7) << 3;     // 0..56
        const size_t gb = (size_t)(m0 + r) * SZ + n0 + c0;
#pragma unroll
        for (int j = 0; j < 2; ++j) {
            f32x4 s = *(const f32x4*)&redF[r * 68 + c0 + j * 4];
#pragma unroll
            for (int ww = 1; ww < 8; ++ww)
                s = s + *(const f32x4*)&redF[ww * 4352 + r * 68 + c0 + j * 4];
            f32x4 xv = *(const f32x4*)(xin + gb + j * 4);
            f32x4 xn = xv * (1.0f - DT) + s;  // dt, cnoise already folded into BTs/Gs
            *(f32x4*)(xout + gb + j * 4) = xn;
            u16x4 yv;
#pragma unroll
            for (int e = 0; e < 4; ++e) {
                float x2 = xn[e] * xn[e];
                yv[e] = f2bf(x2 / (GAM + x2));
            }
            *(u16x4*)(Ynext + gb + j * 4) = yv;
        }
        if (do_noise) {  // convert noise[t+1] for next step's A-operand
#pragma unroll
            for (int j = 0; j < 2; ++j) {
                f32x4 nv = *(const f32x4*)(noise_next + gb + j * 4);
                u16x4 nb;
#pragma unroll
                for (int e = 0; e < 4; ++e) nb[e] = f2bf(nv[e]);
                *(u16x4*)(Nnext + gb + j * 4) = nb;
            }
        }
    }
}

extern "C" void kernel_launch(void* const* d_in, const int* in_sizes, int n_in,
                              void* d_out, int out_size, void* d_ws, size_t ws_size,
                              hipStream_t stream) {
    const float* x = (const float*)d_in[0];
    const float* A = (const float*)d_in[1];
    const float* G = (const float*)d_in[2];
    const float* noise = (const float*)d_in[3];
    float* out = (float*)d_out;
    char* ws = (char*)d_ws;

    float* xbuf = (float*)(ws);                       // 4 MB
    ushort_t* Y0 = (ushort_t*)(ws + (4u << 20));      // 2 MB
    ushort_t* Y1 = (ushort_t*)(ws + (6u << 20));      // 2 MB
    ushort_t* N0 = (ushort_t*)(ws + (8u << 20));      // 2 MB
    ushort_t* N1 = (ushort_t*)(ws + (10u << 20));     // 2 MB
    ushort_t* BTs = (ushort_t*)(ws + (12u << 20));    // 8 MB
    ushort_t* Gsc = (ushort_t*)(ws + (20u << 20));    // 8 MB  (total 28 MB)

    (void)hipFuncSetAttribute((const void*)step_kernel,
                              hipFuncAttributeMaxDynamicSharedMemorySize, 139264);

    prep_kernel<<<dim3(SZ), dim3(256), 0, stream>>>(A, G, BTs, Gsc);
    init_kernel<<<dim3(2048), dim3(256), 0, stream>>>(x, noise, xbuf, Y0, N0);

    ushort_t* Yc = Y0;
    ushort_t* Yn = Y1;
    ushort_t* Nc = N0;
    ushort_t* Nn = N1;
    for (int t = 0; t < NSTEPS; ++t) {
        float* xo = (t == NSTEPS - 1) ? out : xbuf;
        const int dn = (t < NSTEPS - 1) ? 1 : 0;
        const float* nnext = noise + (size_t)(t + 1) * BATCH * SZ;
        step_kernel<<<dim3(256), dim3(512), 139264, stream>>>(
            Yc, Nc, BTs, Gsc, xbuf, xo, Yn, dn ? nnext : noise, Nn, dn);
        ushort_t* tmp = Yc; Yc = Yn; Yn = tmp;
        tmp = Nc; Nc = Nn; Nn = tmp;
    }
}

// Round 2
// 2176.403 us; speedup vs baseline: 1.2752x; 1.2752x over previous
//
#include <hip/hip_runtime.h>
#include <cstdint>

// CVFRLayer: x_{t+1} = (1-dt)x + dt*(nl(x) @ B) + sqrt(dt)*eps*(noise_t @ G^T)
// B = (A @ (I-P) + P)^T  with P block-diagonal (16 blocks of 128, value pval).
// Key identity: B[k,n] = A[n,k] - pval*rowblocksum(A,n,blk(k)) + pval*[blk(n)==blk(k)]
// => GEMM with B-transposed operand stored [N][K] is built from A's ROWS (cheap prep).
// Noise term: (n @ G^T)[m,j] = sum_k n[m,k]*G[j,k] => B-operand is G's rows verbatim.
//
// v3: the noise term is STATE-INDEPENDENT -> hoist it: Z[t] = cnoise*(noise[t] @ G^T)
// computed once as a single [51200 x 2048] @ [2048 x 2048] GEMM (429 GFLOP) at matrix-core
// efficiency into the 1.6GB workspace (419 MB f32). The sequential per-step kernel is then
// a single GEMM (Y @ BTs, K=2048) in the proven v1 structure (wave-private K-split-4,
// K=64 chunks, 128B-row DMAs) + XCD n-slice swizzle + Z added in the epilogue.

typedef unsigned short ushort_t;
typedef __bf16 bf16x8 __attribute__((ext_vector_type(8)));
typedef float f32x4 __attribute__((ext_vector_type(4)));
typedef unsigned short u16x4 __attribute__((ext_vector_type(4)));
typedef unsigned short u16x8 __attribute__((ext_vector_type(8)));

#define SZ 2048
#define BATCH 512
#define NSTEPS 100

static constexpr float DT = 0.03f;
static constexpr float GAM = 0.125f;
// pval = 1/((sqrt(128)+1e-8)^2)
static constexpr float PVAL = (float)(1.0 / (128.0 + 2.2627416997969522e-07));
// sqrt(dt)*epsilon
static constexpr float CNOISE = 0.017320508075688773f;

__device__ __forceinline__ unsigned short f2bf(float f) {
    unsigned int u = __builtin_bit_cast(unsigned int, f);
    return (unsigned short)((u + 0x7fffu + ((u >> 16) & 1u)) >> 16);
}

__device__ __forceinline__ void async16(const void* g, void* l) {
    // global->LDS DMA, 16B per lane; LDS dest = wave-uniform base + lane*16
    __builtin_amdgcn_global_load_lds(
        (__attribute__((address_space(1))) void*)(uintptr_t)g,
        (__attribute__((address_space(3))) void*)(uint32_t)(uintptr_t)l,
        16, 0, 0);
}

// ---------------- prep: build BTs (dt-scaled) and Gs (cnoise-scaled) in bf16 -------------
__global__ __launch_bounds__(256) void prep_kernel(const float* __restrict__ A,
                                                   const float* __restrict__ G,
                                                   ushort_t* __restrict__ BTs,
                                                   ushort_t* __restrict__ Gs) {
    const int n = blockIdx.x;
    const int t = threadIdx.x;
    __shared__ float s16[16];
    const float* arow = A + (size_t)n * SZ;
    f32x4 a0 = *(const f32x4*)(arow + t * 8);
    f32x4 a1 = *(const f32x4*)(arow + t * 8 + 4);
    float ps = a0[0] + a0[1] + a0[2] + a0[3] + a1[0] + a1[1] + a1[2] + a1[3];
#pragma unroll
    for (int m = 1; m < 16; m <<= 1) ps += __shfl_xor(ps, m, 64);
    if ((t & 15) == 0) s16[t >> 4] = ps * PVAL;
    __syncthreads();
    const int seg = t >> 4;
    const float s = s16[seg];
    const float diag = (seg == (n >> 7)) ? PVAL : 0.0f;
    float av[8] = {a0[0], a0[1], a0[2], a0[3], a1[0], a1[1], a1[2], a1[3]};
    u16x8 ov;
#pragma unroll
    for (int i = 0; i < 8; ++i) ov[i] = f2bf(DT * (av[i] - s + diag));
    *(u16x8*)&BTs[(size_t)n * SZ + t * 8] = ov;

    const float* grow = G + (size_t)n * SZ;
    f32x4 g0 = *(const f32x4*)(grow + t * 8);
    f32x4 g1 = *(const f32x4*)(grow + t * 8 + 4);
    float gv[8] = {g0[0], g0[1], g0[2], g0[3], g1[0], g1[1], g1[2], g1[3]};
    u16x8 og;
#pragma unroll
    for (int i = 0; i < 8; ++i) og[i] = f2bf(CNOISE * gv[i]);
    *(u16x8*)&Gs[(size_t)n * SZ + t * 8] = og;
}

// ---------------- convert: ALL noise f32 -> bf16 once (zgemm A-operand) ------------------
__global__ __launch_bounds__(256) void convert_kernel(const float* __restrict__ noise,
                                                      ushort_t* __restrict__ Nb) {
    const size_t total = (size_t)NSTEPS * BATCH * SZ;
    const size_t stride = (size_t)gridDim.x * 256 * 8;
    for (size_t i = ((size_t)blockIdx.x * 256 + threadIdx.x) * 8; i < total; i += stride) {
        f32x4 a = *(const f32x4*)(noise + i);
        f32x4 b = *(const f32x4*)(noise + i + 4);
        u16x8 o;
#pragma unroll
        for (int e = 0; e < 4; ++e) { o[e] = f2bf(a[e]); o[4 + e] = f2bf(b[e]); }
        *(u16x8*)(Nb + i) = o;
    }
}

// ---------------- init: xbuf = x, Y0 = bf16(nl(x)) ---------------------------------------
__global__ __launch_bounds__(256) void init_kernel(const float* __restrict__ x,
                                                   float* __restrict__ xbuf,
                                                   ushort_t* __restrict__ Y0) {
    const size_t i = ((size_t)blockIdx.x * 256 + threadIdx.x) * 4;
    f32x4 xv = *(const f32x4*)(x + i);
    *(f32x4*)(xbuf + i) = xv;
    u16x4 yv;
#pragma unroll
    for (int e = 0; e < 4; ++e) {
        float x2 = xv[e] * xv[e];
        yv[e] = f2bf(x2 / (GAM + x2));
    }
    *(u16x4*)(Y0 + i) = yv;
}

// ---------------- zgemm: Z = Nb @ Gs^T (f32 out), M=51200 N=2048 K=2048 ------------------
// 128x128 tile, BK=64, 4 waves (2x2 quadrants of 64x64), global_load_lds staging with
// XOR swizzle (fetch-side), raw s_barrier + counted vmcnt(8) double-buffered K-loop.
// 64 KB static LDS -> 2 blocks/CU. Grid (16 n, 400 m): x-fastest => 16 consecutive
// blocks share the A-panel (L2 reuse).
__global__ __launch_bounds__(256) void zgemm_kernel(const ushort_t* __restrict__ Nb,
                                                    const ushort_t* __restrict__ Gs,
                                                    float* __restrict__ Z) {
    __shared__ ushort_t sm[2][2][128 * 64];  // [buf][A|B][row][k] = 64 KB
    const int tid = threadIdx.x;
    const int w = tid >> 6;
    const int l = tid & 63;
    const int m0 = blockIdx.y << 7;
    const int n0 = blockIdx.x << 7;

    const char* Ag = (const char*)Nb + (size_t)m0 * 4096;  // row stride 2048 bf16 = 4096B
    const char* Bg = (const char*)Gs + (size_t)n0 * 4096;

    // staging: wave w stages rows [w*32, w*32+32) of both tiles. Lane l -> row l>>3,
    // LDS slot l&7; global chunk fetched there is pre-swizzled: (l&7) ^ (row&7).
    const int srow = l >> 3;
    const int sq = (l & 7) ^ srow;
    const int sgo = srow * 4096 + sq * 16;

    f32x4 acc[4][4] = {};

    auto stage = [&](int ci, int b) {
        const char* Ac = Ag + (size_t)(w * 32) * 4096 + ci * 128;
        const char* Bc = Bg + (size_t)(w * 32) * 4096 + ci * 128;
        ushort_t* dA = &sm[b][0][w * 32 * 64];
        ushort_t* dB = &sm[b][1][w * 32 * 64];
#pragma unroll
        for (int i = 0; i < 4; ++i) {
            async16(Ac + i * 8 * 4096 + sgo, dA + i * 512);
            async16(Bc + i * 8 * 4096 + sgo, dB + i * 512);
        }
    };

    const int wm = w >> 1, wn = w & 1;
    const int lr = l & 15;
    const int q8 = l >> 4;
    const int swz = lr & 7;  // row&7 == lr&7 for rows wm*64 + f*16 + lr

    auto compute = [&](int b) {
        const char* TA = (const char*)&sm[b][0][wm * 64 * 64];
        const char* TB = (const char*)&sm[b][1][wn * 64 * 64];
#pragma unroll
        for (int half = 0; half < 2; ++half) {
            const int qpos = ((((half << 2) | q8) ^ swz) << 4);
            bf16x8 af[4], bfv[4];
#pragma unroll
            for (int f = 0; f < 4; ++f) {
                const int rowb = (f * 16 + lr) * 128;
                af[f] = *(const bf16x8*)(TA + rowb + qpos);
                bfv[f] = *(const bf16x8*)(TB + rowb + qpos);
            }
#pragma unroll
            for (int fr = 0; fr < 4; ++fr)
#pragma unroll
                for (int fc = 0; fc < 4; ++fc)
                    acc[fr][fc] = __builtin_amdgcn_mfma_f32_16x16x32_bf16(
                        af[fr], bfv[fc], acc[fr][fc], 0, 0, 0);
        }
    };

    stage(0, 0);
#pragma unroll 1
    for (int ci = 0; ci < 32; ++ci) {
        if (ci < 31) {
            stage(ci + 1, (ci + 1) & 1);
            // own chunk-ci DMAs (8) drained; chunk ci+1's 8 stay in flight
            asm volatile("s_waitcnt vmcnt(8)" ::: "memory");
        } else {
            asm volatile("s_waitcnt vmcnt(0)" ::: "memory");
        }
        __builtin_amdgcn_s_barrier();            // all waves' chunk-ci loads landed
        __builtin_amdgcn_sched_barrier(0);
        compute(ci & 1);
        __builtin_amdgcn_sched_barrier(0);
        __builtin_amdgcn_s_barrier();            // protect buf before next overwrite
    }

    // epilogue: write f32 quadrant. C/D: row=(lane>>4)*4+reg, col=lane&15
    float* Zr = Z + (size_t)(m0 + wm * 64) * SZ + n0 + wn * 64;
#pragma unroll
    for (int fr = 0; fr < 4; ++fr)
#pragma unroll
        for (int fc = 0; fc < 4; ++fc) {
            const int c = fc * 16 + lr;
#pragma unroll
            for (int reg = 0; reg < 4; ++reg)
                Zr[(size_t)(fr * 16 + q8 * 4 + reg) * SZ + c] = acc[fr][fc][reg];
        }
}

// ---------------- step: GEMM C = Y @ BTs (K=2048) + epilogue with Z ----------------------
// Grid 256 blocks (XCD n-slice swizzle), 256 threads. 64x64 tile. 4 waves, each owns a
// K=512 slice in wave-PRIVATE double-buffered LDS (K=64 chunks, 128B rows) -> no barrier
// in K-loop. Per-XCD working set: B-slice 1MB + Y 2MB < 4MB L2.
__global__ __launch_bounds__(256) void step_kernel(
    const ushort_t* __restrict__ Ycur, const ushort_t* __restrict__ BTs,
    const float* xin, float* xout,
    ushort_t* __restrict__ Ynext, const float* __restrict__ Zt) {
    extern __shared__ ushort_t smem[];  // 128 KiB: 4 waves * 2 bufs * (A 8KB + B 8KB)
    const int tid = threadIdx.x;
    const int w = tid >> 6;
    const int l = tid & 63;

    // XCD swizzle: id&7 = XCD. Each XCD owns a 256-col n-slice x all 8 m-blocks.
    const int id = blockIdx.x;
    const int r5 = id >> 3;                        // 0..31
    const int n0 = (((id & 7) << 2) + (r5 & 3)) << 6;
    const int m0 = (r5 >> 2) << 6;

    // wave w -> K range [w*512, (w+1)*512) elems = byte offset w*1024 within each row
    const char* Ag = (const char*)Ycur + (size_t)m0 * 4096 + w * 1024;
    const char* Bg = (const char*)BTs + (size_t)n0 * 4096 + w * 1024;
    ushort_t* waveLds = smem + w * 16384;  // 32KB per wave (in ushorts)

    // staging: slot s = i*64+l; row = s>>3; pos = s&7; fetched chunk = pos ^ (row&7)
    const int srow = l >> 3;
    const int sq = (l & 7) ^ srow;
    const int sgo = srow * 4096 + sq * 16;

    f32x4 acc[4][4] = {};

    auto stage = [&](int ci, int b) {
        const char* Ac = Ag + ci * 128;            // K=64 -> 128 bytes
        const char* Bc = Bg + ci * 128;
        ushort_t* dA = waveLds + b * 8192;
        ushort_t* dB = dA + 4096;
#pragma unroll
        for (int i = 0; i < 8; ++i) {
            async16(Ac + i * 32768 + sgo, dA + i * 512);
            async16(Bc + i * 32768 + sgo, dB + i * 512);
        }
    };

    const int lr = l & 15;
    const int q8 = l >> 4;
    const int swz = lr & 7;

    auto compute = [&](int b) {
        const char* TA = (const char*)waveLds + b * 16384;
        const char* TB = TA + 8192;
#pragma unroll
        for (int half = 0; half < 2; ++half) {
            const int qpos = ((((half << 2) | q8) ^ swz) << 4);
            bf16x8 af[4], bfv[4];
#pragma unroll
            for (int f = 0; f < 4; ++f) {
                const int rowb = (f * 16 + lr) * 128;
                af[f] = *(const bf16x8*)(TA + rowb + qpos);
                bfv[f] = *(const bf16x8*)(TB + rowb + qpos);
            }
#pragma unroll
            for (int fr = 0; fr < 4; ++fr)
#pragma unroll
                for (int fc = 0; fc < 4; ++fc)
                    acc[fr][fc] = __builtin_amdgcn_mfma_f32_16x16x32_bf16(
                        af[fr], bfv[fc], acc[fr][fc], 0, 0, 0);
        }
    };

    stage(0, 0);
#pragma unroll 2
    for (int ci = 0; ci < 8; ++ci) {
        if (ci < 7) {
            stage(ci + 1, (ci + 1) & 1);
            // oldest-16 (= chunk ci's DMAs) drained; chunk ci+1's 16 stay in flight
            asm volatile("s_waitcnt vmcnt(16)" ::: "memory");
        } else {
            asm volatile("s_waitcnt vmcnt(0)" ::: "memory");
        }
        compute(ci & 1);
    }

    // cross-wave K-split reduction through LDS (padded stride 68 floats -> no conflicts)
    __syncthreads();
    float* redF = (float*)smem;
    {
        const int base = w * 4352;
#pragma unroll
        for (int fr = 0; fr < 4; ++fr)
#pragma unroll
            for (int fc = 0; fc < 4; ++fc) {
                const int c = fc * 16 + lr;
                const int rb = fr * 16 + q8 * 4;  // C/D: row=(lane>>4)*4+reg, col=lane&15
#pragma unroll
                for (int reg = 0; reg < 4; ++reg)
                    redF[base + (rb + reg) * 68 + c] = acc[fr][fc][reg];
            }
    }
    __syncthreads();
    {
        const int r = tid >> 2;
        const int c0 = (tid & 3) << 4;
        const size_t gb = (size_t)(m0 + r) * SZ + n0 + c0;
#pragma unroll
        for (int j = 0; j < 4; ++j) {
            f32x4 s = *(const f32x4*)&redF[0 * 4352 + r * 68 + c0 + j * 4];
            s = s + *(const f32x4*)&redF[1 * 4352 + r * 68 + c0 + j * 4];
            s = s + *(const f32x4*)&redF[2 * 4352 + r * 68 + c0 + j * 4];
            s = s + *(const f32x4*)&redF[3 * 4352 + r * 68 + c0 + j * 4];
            f32x4 xv = *(const f32x4*)(xin + gb + j * 4);
            f32x4 zv = *(const f32x4*)(Zt + gb + j * 4);
            f32x4 xn = xv * (1.0f - DT) + s + zv;  // dt in BTs, cnoise in Z
            *(f32x4*)(xout + gb + j * 4) = xn;
            u16x4 yv;
#pragma unroll
            for (int e = 0; e < 4; ++e) {
                float x2 = xn[e] * xn[e];
                yv[e] = f2bf(x2 / (GAM + x2));
            }
            *(u16x4*)(Ynext + gb + j * 4) = yv;
        }
    }
}

extern "C" void kernel_launch(void* const* d_in, const int* in_sizes, int n_in,
                              void* d_out, int out_size, void* d_ws, size_t ws_size,
                              hipStream_t stream) {
    const float* x = (const float*)d_in[0];
    const float* A = (const float*)d_in[1];
    const float* G = (const float*)d_in[2];
    const float* noise = (const float*)d_in[3];
    float* out = (float*)d_out;
    char* ws = (char*)d_ws;

    float* xbuf = (float*)(ws);                        // 4 MB
    ushort_t* Y0 = (ushort_t*)(ws + (4u << 20));       // 2 MB
    ushort_t* Y1 = (ushort_t*)(ws + (6u << 20));       // 2 MB
    ushort_t* BTs = (ushort_t*)(ws + (8u << 20));      // 8 MB
    ushort_t* Gsc = (ushort_t*)(ws + (16u << 20));     // 8 MB
    float* Zall = (float*)(ws + (24u << 20));          // 419.5 MB (100*512*2048 f32)
    ushort_t* Nb = (ushort_t*)(ws + (448ull << 20));   // 209.7 MB (100*512*2048 bf16)

    (void)hipFuncSetAttribute((const void*)step_kernel,
                              hipFuncAttributeMaxDynamicSharedMemorySize, 131072);

    prep_kernel<<<dim3(SZ), dim3(256), 0, stream>>>(A, G, BTs, Gsc);
    convert_kernel<<<dim3(2048), dim3(256), 0, stream>>>(noise, Nb);
    init_kernel<<<dim3(1024), dim3(256), 0, stream>>>(x, xbuf, Y0);
    zgemm_kernel<<<dim3(16, 400), dim3(256), 0, stream>>>(Nb, Gsc, Zall);

    ushort_t* Yc = Y0;
    ushort_t* Yn = Y1;
    for (int t = 0; t < NSTEPS; ++t) {
        float* xo = (t == NSTEPS - 1) ? out : xbuf;
        step_kernel<<<dim3(256), dim3(256), 131072, stream>>>(
            Yc, BTs, xbuf, xo, Yn, Zall + (size_t)t * BATCH * SZ);
        ushort_t* tmp = Yc; Yc = Yn; Yn = tmp;
    }
}